// Round 5
// baseline (294.578 us; speedup 1.0000x reference)
//
#include <hip/hip_runtime.h>
#include <math.h>

typedef __bf16 bf16;
typedef __attribute__((ext_vector_type(4))) __bf16 bf16x4;
typedef __attribute__((ext_vector_type(8))) __bf16 bf16x8;
typedef __attribute__((ext_vector_type(4))) float f32x4;
typedef __attribute__((ext_vector_type(4))) unsigned int u32x4;

#define AS1 __attribute__((address_space(1)))
#define AS3 __attribute__((address_space(3)))

__device__ __forceinline__ void gload16(const void* g, void* l) {
  __builtin_amdgcn_global_load_lds((const AS1 void*)g, (AS3 void*)l, 16, 0, 0);
}

__device__ __forceinline__ unsigned int pack2bf(float lo, float hi) {
  union { unsigned int u; __bf16 h[2]; } w;
  w.h[0] = (bf16)lo; w.h[1] = (bf16)hi;
  return w.u;
}

#define DIM 768
#define NH  12
#define HD  64
#define B_  4
#define N_  2048
#define M_  (B_*N_)   // 8192 tokens
#define BH_ (B_*NH)   // 48 (b,h) pairs

// Q pre-scale: 1/sqrt(64) * log2(e)  -> softmax in base-2 (saves a mul/score)
#define QSCALE 0.1803368801111244f

// ---------------------------------------------------------------- convert
__global__ void convert_all(const float4* __restrict__ x,
                            const float4* __restrict__ wq,
                            const float4* __restrict__ wp,
                            bf16x4* __restrict__ xb,
                            bf16x4* __restrict__ wqb,
                            bf16x4* __restrict__ wpb) {
  const int nx = M_*DIM/4, nq = 3*DIM*DIM/4, np = DIM*DIM/4;
  const int total = nx + nq + np;
  for (int i = blockIdx.x*blockDim.x + threadIdx.x; i < total;
       i += gridDim.x*blockDim.x) {
    float4 v; bf16x4* dst;
    if (i < nx)           { v = x[i];         dst = xb  + i;         }
    else if (i < nx + nq) { v = wq[i-nx];     dst = wqb + (i-nx);    }
    else                  { v = wp[i-nx-nq];  dst = wpb + (i-nx-nq); }
    bf16x4 o = { (bf16)v.x, (bf16)v.y, (bf16)v.z, (bf16)v.w };
    *dst = o;
  }
}

// ---------------------------------------------------------------- GEMM (B^T)
template<int EPI>
__global__ __launch_bounds__(256)
void gemm_bt(const bf16* __restrict__ A, const bf16* __restrict__ B,
             bf16* __restrict__ qv, bf16* __restrict__ kv_, bf16* __restrict__ vt,
             const float* __restrict__ bprj, float* __restrict__ out) {
  constexpr int K = DIM;
  __shared__ __align__(16) bf16 As[128*32];
  __shared__ __align__(16) bf16 Bs[128*32];
  const int tid = threadIdx.x;
  const int wave = tid >> 6, lane = tid & 63;
  const int l15 = lane & 15, lg = lane >> 4;
  const int wr = wave >> 1, wc = wave & 1;
  const int m0 = blockIdx.y * 128, n0 = blockIdx.x * 128;

  f32x4 acc[4][4] = {};
  const int pbase = wave*2048 + lane*16;

  for (int kb = 0; kb < K; kb += 32) {
    __syncthreads();
#pragma unroll
    for (int i = 0; i < 2; i++) {
      int p = pbase + i*1024;
      int row = p >> 6, cb = p & 63;
      gload16((const char*)A + ((size_t)(m0+row)*K + kb)*2 + cb, (char*)As + p);
      gload16((const char*)B + ((size_t)(n0+row)*K + kb)*2 + cb, (char*)Bs + p);
    }
    __syncthreads();
    bf16x8 af[4], bfr[4];
#pragma unroll
    for (int f = 0; f < 4; f++) {
      af[f]  = *(const bf16x8*)(As + (wr*64 + f*16 + l15)*32 + lg*8);
      bfr[f] = *(const bf16x8*)(Bs + (wc*64 + f*16 + l15)*32 + lg*8);
    }
#pragma unroll
    for (int fm = 0; fm < 4; fm++)
#pragma unroll
      for (int fn = 0; fn < 4; fn++)
        acc[fm][fn] = __builtin_amdgcn_mfma_f32_16x16x32_bf16(af[fm], bfr[fn],
                                                              acc[fm][fn], 0, 0, 0);
  }

  if (EPI == 0) {
    const int c0 = n0 + wc*64;
    const int t = c0 / DIM;
    const int hcol = (c0 % DIM) >> 6;
#pragma unroll
    for (int fm = 0; fm < 4; fm++) {
      const int gm0 = m0 + wr*64 + fm*16 + (lg<<2);
      const int b = gm0 >> 11, nn0 = gm0 & 2047;
      const size_t bh = (size_t)b*NH + hcol;
#pragma unroll
      for (int fn = 0; fn < 4; fn++) {
        const int d = fn*16 + l15;
        if (t == 0) {
#pragma unroll
          for (int r = 0; r < 4; r++)
            qv[(bh*N_ + nn0 + r)*HD + d] = (bf16)(acc[fm][fn][r] * QSCALE);
        } else if (t == 1) {
#pragma unroll
          for (int r = 0; r < 4; r++)
            kv_[(bh*N_ + nn0 + r)*HD + d] = (bf16)acc[fm][fn][r];
        } else {
          bf16x4 pk = { (bf16)acc[fm][fn][0], (bf16)acc[fm][fn][1],
                        (bf16)acc[fm][fn][2], (bf16)acc[fm][fn][3] };
          *(bf16x4*)(vt + (bh*HD + d)*N_ + nn0) = pk;
        }
      }
    }
  } else {
#pragma unroll
    for (int fn = 0; fn < 4; fn++) {
      const int c = n0 + wc*64 + fn*16 + l15;
      const float bias = bprj[c];
#pragma unroll
      for (int fm = 0; fm < 4; fm++) {
        const int gm0 = m0 + wr*64 + fm*16 + (lg<<2);
#pragma unroll
        for (int r = 0; r < 4; r++)
          out[(size_t)(gm0 + r)*DIM + c] = acc[fm][fn][r] + bias;
      }
    }
  }
}

// ---------------------------------------------------------------- attention
// Swapped-QK^T flash attention, base-2 softmax. grid (N/64, BH) = 1536 blocks,
// 4 waves x 16 q-rows, KVBLK=64, double-buffered staging. LDS 32 KiB ->
// 5 blocks/CU -> ~20 waves/CU (was 12): same total VALU/MFMA work, 2x overlap.
__global__ __launch_bounds__(256)
void attn_fwd(const bf16* __restrict__ Q, const bf16* __restrict__ Kb,
              const bf16* __restrict__ Vt, bf16* __restrict__ AO) {
  __shared__ __align__(16) bf16 Ks[2][64*64];
  __shared__ __align__(16) bf16 Vs[2][64*64];
  const int tid = threadIdx.x;
  const int wave = tid >> 6, lane = tid & 63;
  const int l15 = lane & 15, lg = lane >> 4;
  const int bh = blockIdx.y;
  const int b = bh / NH, h = bh % NH;
  const int q0 = blockIdx.x*64 + wave*16;

  // Q fragments (B-operand: lane holds Q[q=l15][d=lg*8..+8]); QSCALE pre-folded
  const bf16* Qbase = Q + (size_t)bh*N_*HD;
  bf16x8 qf[2];
#pragma unroll
  for (int ks = 0; ks < 2; ks++)
    qf[ks] = *(const bf16x8*)(Qbase + (size_t)(q0 + l15)*HD + ks*32 + lg*8);

  f32x4 Ot[4] = {};                    // O^T: row=d (reg axis), col=q=l15
  float m_ = -INFINITY, l_ = 0.f;

  const char* Kg = (const char*)(Kb + (size_t)bh*N_*HD);
  const char* Vg = (const char*)(Vt + (size_t)bh*HD*N_);
  const int pbase = wave*2048 + lane*16;
  const bool lower = (lane < 32);
  const bool q03 = (lg == 0) || (lg == 3);

#define STAGE(buf, kv)                                                      \
  {                                                                         \
    _Pragma("unroll")                                                       \
    for (int i = 0; i < 2; i++) {                                           \
      int p = pbase + i*1024;                                               \
      int r = p >> 7, cbp = p & 127;                                        \
      int cb = cbp ^ ((r & 7) << 4);                                        \
      gload16(Kg + (size_t)((kv) + r)*128 + cb, (char*)Ks[buf] + p);        \
      gload16(Vg + (size_t)r*(N_*2) + (kv)*2 + cb, (char*)Vs[buf] + p);     \
    }                                                                       \
  }

  STAGE(0, 0);

  for (int t = 0; t < N_/64; ++t) {
    __syncthreads();                       // drains own vmcnt -> tile t ready
    if (t + 1 < N_/64) STAGE((t+1)&1, (t+1)*64);
    const char* Kc = (const char*)Ks[t&1];
    const char* Vc = (const char*)Vs[t&1];

    // S^T = K * Q^T   (S pre-scaled by log2e via Q)
    f32x4 s[4] = {};
#pragma unroll
    for (int ks = 0; ks < 2; ks++) {
      bf16x8 kf[4];
#pragma unroll
      for (int fk = 0; fk < 4; fk++) {
        int r = fk*16 + l15;
        int cb = (ks*64 + lg*16) ^ ((r & 7) << 4);
        kf[fk] = *(const bf16x8*)(Kc + r*128 + cb);
      }
#pragma unroll
      for (int fk = 0; fk < 4; fk++)
        s[fk] = __builtin_amdgcn_mfma_f32_16x16x32_bf16(kf[fk], qf[ks],
                                                        s[fk], 0, 0, 0);
    }

    // base-2 online softmax (lane-local column; 2 shfls per reduce)
    f32x4 m01, m23, m4;
#pragma unroll
    for (int r = 0; r < 4; r++) {
      m01[r] = fmaxf(s[0][r], s[1][r]);
      m23[r] = fmaxf(s[2][r], s[3][r]);
      m4[r]  = fmaxf(m01[r], m23[r]);
    }
    float mx = fmaxf(fmaxf(m4[0], m4[1]), fmaxf(m4[2], m4[3]));
    mx = fmaxf(mx, __shfl_xor(mx, 16));
    mx = fmaxf(mx, __shfl_xor(mx, 32));
    if (!__all(mx - m_ <= 8.0f)) {        // defer-max (8 bits ~ 5.5 nats)
      float mn = fmaxf(m_, mx);
      float c = exp2f(m_ - mn);
      m_ = mn; l_ *= c;
#pragma unroll
      for (int fd = 0; fd < 4; fd++) Ot[fd] *= c;
    }
    float pe[4][4]; float rs = 0.f;
#pragma unroll
    for (int fk = 0; fk < 4; fk++)
#pragma unroll
      for (int r = 0; r < 4; r++) {
        pe[fk][r] = exp2f(s[fk][r] - m_);
        rs += pe[fk][r];
      }
    rs += __shfl_xor(rs, 16);
    rs += __shfl_xor(rs, 32);
    l_ += rs;

    // pack pairs: pk[fk][rp] holds kk = fk*16 + lg*4 + {2rp, 2rp+1}
    unsigned int pk[4][2];
#pragma unroll
    for (int fk = 0; fk < 4; fk++)
#pragma unroll
      for (int rp = 0; rp < 2; rp++)
        pk[fk][rp] = pack2bf(pe[fk][2*rp], pe[fk][2*rp+1]);

    // butterfly redistribution to B-operand layout (verified fragment map)
    unsigned int Eo[2][2], Er[2][2], rB[2][2];
#pragma unroll
    for (int fh = 0; fh < 2; fh++)
#pragma unroll
      for (int rp = 0; rp < 2; rp++) {
        unsigned int vA = lower ? pk[2*fh+1][rp] : pk[2*fh][rp];
        Er[fh][rp] = __shfl_xor((int)vA, 32);
        Eo[fh][rp] = lower ? pk[2*fh][rp] : pk[2*fh+1][rp];
      }
#pragma unroll
    for (int fh = 0; fh < 2; fh++)
#pragma unroll
      for (int rp = 0; rp < 2; rp++) {
        unsigned int vB = q03 ? Er[fh][rp] : Eo[fh][rp];
        rB[fh][rp] = __shfl_xor((int)vB, 16);
      }
    unsigned int paw[2][4];
#pragma unroll
    for (int ks = 0; ks < 2; ks++)
#pragma unroll
      for (int rp = 0; rp < 2; rp++) {
        paw[ks][rp]   = (lg == 0) ? Eo[ks][rp] :
                        (lg == 1) ? rB[ks][rp] :
                        (lg == 2) ? Er[ks][rp] : rB[ks][rp];
        paw[ks][2+rp] = (lg == 0) ? rB[ks][rp] :
                        (lg == 1) ? Er[ks][rp] :
                        (lg == 2) ? rB[ks][rp] : Eo[ks][rp];
      }

    // O^T += V^T * P
#pragma unroll
    for (int ks = 0; ks < 2; ks++) {
      bf16x8 vb[4];
#pragma unroll
      for (int fd = 0; fd < 4; fd++) {
        int r = fd*16 + l15;
        int cb = (ks*64 + lg*16) ^ ((r & 7) << 4);
        vb[fd] = *(const bf16x8*)(Vc + r*128 + cb);
      }
      u32x4 tw = { paw[ks][0], paw[ks][1], paw[ks][2], paw[ks][3] };
      bf16x8 pa = __builtin_bit_cast(bf16x8, tw);
#pragma unroll
      for (int fd = 0; fd < 4; fd++)
        Ot[fd] = __builtin_amdgcn_mfma_f32_16x16x32_bf16(vb[fd], pa,
                                                         Ot[fd], 0, 0, 0);
    }
  }

  // normalize + store: lane holds column q=l15 of O^T; rows d = fd*16 + lg*4 + r
  const float inv = 1.f / l_;
  const int qrow = q0 + l15;
#pragma unroll
  for (int fd = 0; fd < 4; fd++) {
    bf16x4 pk4 = { (bf16)(Ot[fd][0]*inv), (bf16)(Ot[fd][1]*inv),
                   (bf16)(Ot[fd][2]*inv), (bf16)(Ot[fd][3]*inv) };
    *(bf16x4*)(AO + ((size_t)b*N_ + qrow)*DIM + h*HD + fd*16 + lg*4) = pk4;
  }
#undef STAGE
}

// ---------------------------------------------------------------- launch
extern "C" void kernel_launch(void* const* d_in, const int* in_sizes, int n_in,
                              void* d_out, int out_size, void* d_ws, size_t ws_size,
                              hipStream_t stream) {
  const float* x     = (const float*)d_in[0];
  // d_in[1] = xpos : unused by the reference
  const float* wqkv  = (const float*)d_in[2];
  const float* wproj = (const float*)d_in[3];
  const float* bproj = (const float*)d_in[4];
  float* out = (float*)d_out;

  char* ws = (char*)d_ws;
  bf16* xb    = (bf16*)ws;  ws += (size_t)M_*DIM*2;
  bf16* wqkvb = (bf16*)ws;  ws += (size_t)3*DIM*DIM*2;
  bf16* wprojb= (bf16*)ws;  ws += (size_t)DIM*DIM*2;
  bf16* qb    = (bf16*)ws;  ws += (size_t)BH_*N_*HD*2;
  bf16* kb    = (bf16*)ws;  ws += (size_t)BH_*N_*HD*2;
  bf16* vtb   = (bf16*)ws;  ws += (size_t)BH_*HD*N_*2;
  bf16* aob   = (bf16*)ws;  ws += (size_t)M_*DIM*2;

  convert_all<<<dim3(2048), dim3(256), 0, stream>>>(
      (const float4*)x, (const float4*)wqkv, (const float4*)wproj,
      (bf16x4*)xb, (bf16x4*)wqkvb, (bf16x4*)wprojb);

  gemm_bt<0><<<dim3(3*DIM/128, M_/128), dim3(256), 0, stream>>>(
      xb, wqkvb, qb, kb, vtb, nullptr, nullptr);

  attn_fwd<<<dim3(N_/64, BH_), dim3(256), 0, stream>>>(qb, kb, vtb, aob);

  gemm_bt<1><<<dim3(DIM/128, M_/128), dim3(256), 0, stream>>>(
      aob, wprojb, nullptr, nullptr, nullptr, bproj, out);
}

// Round 6
// 287.609 us; speedup vs baseline: 1.0242x; 1.0242x over previous
//
#include <hip/hip_runtime.h>
#include <math.h>

typedef __bf16 bf16;
typedef __attribute__((ext_vector_type(4))) __bf16 bf16x4;
typedef __attribute__((ext_vector_type(8))) __bf16 bf16x8;
typedef __attribute__((ext_vector_type(4))) float f32x4;
typedef __attribute__((ext_vector_type(16))) float f32x16;
typedef __attribute__((ext_vector_type(4))) unsigned int u32x4;

#define AS1 __attribute__((address_space(1)))
#define AS3 __attribute__((address_space(3)))

__device__ __forceinline__ void gload16(const void* g, void* l) {
  __builtin_amdgcn_global_load_lds((const AS1 void*)g, (AS3 void*)l, 16, 0, 0);
}

__device__ __forceinline__ unsigned int pack2bf(float lo, float hi) {
  union { unsigned int u; __bf16 h[2]; } w;
  w.h[0] = (bf16)lo; w.h[1] = (bf16)hi;
  return w.u;
}

#define DIM 768
#define NH  12
#define HD  64
#define B_  4
#define N_  2048
#define M_  (B_*N_)   // 8192 tokens
#define BH_ (B_*NH)   // 48 (b,h) pairs

// Q pre-scale: 1/sqrt(64) * log2(e)  -> softmax in base-2
#define QSCALE 0.1803368801111244f

// ---------------------------------------------------------------- convert
__global__ void convert_all(const float4* __restrict__ x,
                            const float4* __restrict__ wq,
                            const float4* __restrict__ wp,
                            bf16x4* __restrict__ xb,
                            bf16x4* __restrict__ wqb,
                            bf16x4* __restrict__ wpb) {
  const int nx = M_*DIM/4, nq = 3*DIM*DIM/4, np = DIM*DIM/4;
  const int total = nx + nq + np;
  for (int i = blockIdx.x*blockDim.x + threadIdx.x; i < total;
       i += gridDim.x*blockDim.x) {
    float4 v; bf16x4* dst;
    if (i < nx)           { v = x[i];         dst = xb  + i;         }
    else if (i < nx + nq) { v = wq[i-nx];     dst = wqb + (i-nx);    }
    else                  { v = wp[i-nx-nq];  dst = wpb + (i-nx-nq); }
    bf16x4 o = { (bf16)v.x, (bf16)v.y, (bf16)v.z, (bf16)v.w };
    *dst = o;
  }
}

// ---------------------------------------------------------------- GEMM (B^T)
template<int EPI>
__global__ __launch_bounds__(256)
void gemm_bt(const bf16* __restrict__ A, const bf16* __restrict__ B,
             bf16* __restrict__ qv, bf16* __restrict__ kv_, bf16* __restrict__ vt,
             const float* __restrict__ bprj, float* __restrict__ out) {
  constexpr int K = DIM;
  __shared__ __align__(16) bf16 As[128*32];
  __shared__ __align__(16) bf16 Bs[128*32];
  const int tid = threadIdx.x;
  const int wave = tid >> 6, lane = tid & 63;
  const int l15 = lane & 15, lg = lane >> 4;
  const int wr = wave >> 1, wc = wave & 1;
  const int m0 = blockIdx.y * 128, n0 = blockIdx.x * 128;

  f32x4 acc[4][4] = {};
  const int pbase = wave*2048 + lane*16;

  for (int kb = 0; kb < K; kb += 32) {
    __syncthreads();
#pragma unroll
    for (int i = 0; i < 2; i++) {
      int p = pbase + i*1024;
      int row = p >> 6, cb = p & 63;
      gload16((const char*)A + ((size_t)(m0+row)*K + kb)*2 + cb, (char*)As + p);
      gload16((const char*)B + ((size_t)(n0+row)*K + kb)*2 + cb, (char*)Bs + p);
    }
    __syncthreads();
    bf16x8 af[4], bfr[4];
#pragma unroll
    for (int f = 0; f < 4; f++) {
      af[f]  = *(const bf16x8*)(As + (wr*64 + f*16 + l15)*32 + lg*8);
      bfr[f] = *(const bf16x8*)(Bs + (wc*64 + f*16 + l15)*32 + lg*8);
    }
#pragma unroll
    for (int fm = 0; fm < 4; fm++)
#pragma unroll
      for (int fn = 0; fn < 4; fn++)
        acc[fm][fn] = __builtin_amdgcn_mfma_f32_16x16x32_bf16(af[fm], bfr[fn],
                                                              acc[fm][fn], 0, 0, 0);
  }

  if (EPI == 0) {
    const int c0 = n0 + wc*64;
    const int t = c0 / DIM;
    const int hcol = (c0 % DIM) >> 6;
#pragma unroll
    for (int fm = 0; fm < 4; fm++) {
      const int gm0 = m0 + wr*64 + fm*16 + (lg<<2);
      const int b = gm0 >> 11, nn0 = gm0 & 2047;
      const size_t bh = (size_t)b*NH + hcol;
#pragma unroll
      for (int fn = 0; fn < 4; fn++) {
        const int d = fn*16 + l15;
        if (t == 0) {
#pragma unroll
          for (int r = 0; r < 4; r++)
            qv[(bh*N_ + nn0 + r)*HD + d] = (bf16)(acc[fm][fn][r] * QSCALE);
        } else if (t == 1) {
#pragma unroll
          for (int r = 0; r < 4; r++)
            kv_[(bh*N_ + nn0 + r)*HD + d] = (bf16)acc[fm][fn][r];
        } else {
          bf16x4 pk = { (bf16)acc[fm][fn][0], (bf16)acc[fm][fn][1],
                        (bf16)acc[fm][fn][2], (bf16)acc[fm][fn][3] };
          *(bf16x4*)(vt + (bh*HD + d)*N_ + nn0) = pk;
        }
      }
    }
  } else {
#pragma unroll
    for (int fn = 0; fn < 4; fn++) {
      const int c = n0 + wc*64 + fn*16 + l15;
      const float bias = bprj[c];
#pragma unroll
      for (int fm = 0; fm < 4; fm++) {
        const int gm0 = m0 + wr*64 + fm*16 + (lg<<2);
#pragma unroll
        for (int r = 0; r < 4; r++)
          out[(size_t)(gm0 + r)*DIM + c] = acc[fm][fn][r] + bias;
      }
    }
  }
}

// ---------------------------------------------------------------- attention
// Swapped-QK^T flash attention with 32x32x16 MFMA, base-2 softmax.
// grid (N/128, BH) = 768 blocks, 4 waves x 32 q-rows, KVBLK=64, dbuf staging.
// S^T = mfma32(K, Q^T): col=l31=q, rows kk on regs/half-wave. Softmax reduce =
// 31 lane-local fmax + 1 shfl_xor(32). P -> B-operand: ONE half-wave exchange
// (2 shfl_xor(32) per kk-16 step). O^T = mfma32(V^T, P): d rows on regs.
__global__ __launch_bounds__(256)
void attn_fwd(const bf16* __restrict__ Q, const bf16* __restrict__ Kb,
              const bf16* __restrict__ Vt, bf16* __restrict__ AO) {
  __shared__ __align__(16) bf16 Ks[2][64*64];
  __shared__ __align__(16) bf16 Vs[2][64*64];
  const int tid = threadIdx.x;
  const int wave = tid >> 6, lane = tid & 63;
  const int l31 = lane & 31, h = lane >> 5;
  const int bh = blockIdx.y;
  const int b = bh / NH, hed = bh % NH;
  const int q0 = blockIdx.x*128 + wave*32;

  // Q fragments (B-operand): qf[dk][e] = Q[q0+l31][dk*16 + h*8 + e]; QSCALE folded
  const bf16* Qbase = Q + ((size_t)bh*N_ + q0 + l31)*HD;
  bf16x8 qf[4];
#pragma unroll
  for (int dk = 0; dk < 4; dk++)
    qf[dk] = *(const bf16x8*)(Qbase + dk*16 + h*8);

  f32x16 Ot[2] = {};                   // O^T: d = dt*32 + (reg&3)+8*(reg>>2)+4h, q=l31
  float m_ = -INFINITY, l_ = 0.f;

  const char* Kg = (const char*)(Kb + (size_t)bh*N_*HD);
  const char* Vg = (const char*)(Vt + (size_t)bh*HD*N_);
  const int pbase = wave*2048 + lane*16;

#define STAGE(buf, kv)                                                      \
  {                                                                         \
    _Pragma("unroll")                                                       \
    for (int i = 0; i < 2; i++) {                                           \
      int p = pbase + i*1024;                                               \
      int r = p >> 7, cbp = p & 127;                                        \
      int cb = cbp ^ ((r & 7) << 4);                                        \
      gload16(Kg + (size_t)((kv) + r)*128 + cb, (char*)Ks[buf] + p);        \
      gload16(Vg + (size_t)r*(N_*2) + (kv)*2 + cb, (char*)Vs[buf] + p);     \
    }                                                                       \
  }

  STAGE(0, 0);

  for (int t = 0; t < N_/64; ++t) {
    __syncthreads();                       // drains own vmcnt -> tile t ready
    if (t + 1 < N_/64) STAGE((t+1)&1, (t+1)*64);
    const char* Kc = (const char*)Ks[t&1];
    const char* Vc = (const char*)Vs[t&1];

    // S^T = K * Q^T  (pre-scaled by log2e/8 via Q)
    f32x16 s[2] = {};
#pragma unroll
    for (int kkt = 0; kkt < 2; kkt++) {
      const int r = kkt*32 + l31;
      const int sw = (r & 7) << 4;
#pragma unroll
      for (int dk = 0; dk < 4; dk++) {
        bf16x8 kf = *(const bf16x8*)(Kc + r*128 + ((dk*32 + h*16) ^ sw));
        s[kkt] = __builtin_amdgcn_mfma_f32_32x32x16_bf16(kf, qf[dk],
                                                         s[kkt], 0, 0, 0);
      }
    }

    // base-2 online softmax: q fully on lane axis; kk = lane-local + partner half
    float mx = s[0][0];
#pragma unroll
    for (int i = 1; i < 16; i++) mx = fmaxf(mx, s[0][i]);
#pragma unroll
    for (int i = 0; i < 16; i++) mx = fmaxf(mx, s[1][i]);
    mx = fmaxf(mx, __shfl_xor(mx, 32));
    if (!__all(mx - m_ <= 8.0f)) {        // defer-max
      float mn = fmaxf(m_, mx);
      float c = exp2f(m_ - mn);
      m_ = mn; l_ *= c;
#pragma unroll
      for (int dt = 0; dt < 2; dt++)
#pragma unroll
        for (int i = 0; i < 16; i++) Ot[dt][i] *= c;
    }
    float rs = 0.f;
#pragma unroll
    for (int kkt = 0; kkt < 2; kkt++)
#pragma unroll
      for (int i = 0; i < 16; i++) {
        float p = exp2f(s[kkt][i] - m_);
        s[kkt][i] = p;                     // reuse s as P storage
        rs += p;
      }
    rs += __shfl_xor(rs, 32);
    l_ += rs;

    // P -> B-operand words pw[st][w] (kk-16 window st): pack pairs, ONE
    // half-wave exchange. Window offsets held: h=0 {0..3,8..11}, h=1 {4..7,12..15}.
    // B word w at h needs {h*8+2w, h*8+2w+1}.
    unsigned int pw[4][4];
#pragma unroll
    for (int st = 0; st < 4; st++) {
      const int kkt = st >> 1, base = (st & 1) * 8;
      unsigned int a0 = pack2bf(s[kkt][base+0], s[kkt][base+1]);  // off 4h+{0,1}
      unsigned int a1 = pack2bf(s[kkt][base+2], s[kkt][base+3]);  // off 4h+{2,3}
      unsigned int b0 = pack2bf(s[kkt][base+4], s[kkt][base+5]);  // off 4h+8+{0,1}
      unsigned int b1 = pack2bf(s[kkt][base+6], s[kkt][base+7]);  // off 4h+8+{2,3}
      unsigned int r0 = __shfl_xor((int)(h ? a0 : b0), 32);
      unsigned int r1 = __shfl_xor((int)(h ? a1 : b1), 32);
      pw[st][0] = h ? r0 : a0;
      pw[st][1] = h ? r1 : a1;
      pw[st][2] = h ? b0 : r0;
      pw[st][3] = h ? b1 : r1;
    }

    // O^T += V^T * P
#pragma unroll
    for (int dt = 0; dt < 2; dt++) {
      const int r = dt*32 + l31;
      const int sw = (r & 7) << 4;
#pragma unroll
      for (int st = 0; st < 4; st++) {
        bf16x8 vf = *(const bf16x8*)(Vc + r*128 + ((st*32 + h*16) ^ sw));
        u32x4 tw = { pw[st][0], pw[st][1], pw[st][2], pw[st][3] };
        bf16x8 pa = __builtin_bit_cast(bf16x8, tw);
        Ot[dt] = __builtin_amdgcn_mfma_f32_32x32x16_bf16(vf, pa,
                                                         Ot[dt], 0, 0, 0);
      }
    }
  }

  // normalize + store: lane holds column q=l31; d = dt*32 + 8*g + 4h + (0..3)
  const float inv = 1.f / l_;
  bf16* aoBase = AO + ((size_t)b*N_ + q0 + l31)*DIM + hed*HD;
#pragma unroll
  for (int dt = 0; dt < 2; dt++)
#pragma unroll
    for (int g = 0; g < 4; g++) {
      bf16x4 o4 = { (bf16)(Ot[dt][4*g+0]*inv), (bf16)(Ot[dt][4*g+1]*inv),
                    (bf16)(Ot[dt][4*g+2]*inv), (bf16)(Ot[dt][4*g+3]*inv) };
      *(bf16x4*)(aoBase + dt*32 + 8*g + 4*h) = o4;
    }
#undef STAGE
}

// ---------------------------------------------------------------- launch
extern "C" void kernel_launch(void* const* d_in, const int* in_sizes, int n_in,
                              void* d_out, int out_size, void* d_ws, size_t ws_size,
                              hipStream_t stream) {
  const float* x     = (const float*)d_in[0];
  // d_in[1] = xpos : unused by the reference
  const float* wqkv  = (const float*)d_in[2];
  const float* wproj = (const float*)d_in[3];
  const float* bproj = (const float*)d_in[4];
  float* out = (float*)d_out;

  char* ws = (char*)d_ws;
  bf16* xb    = (bf16*)ws;  ws += (size_t)M_*DIM*2;
  bf16* wqkvb = (bf16*)ws;  ws += (size_t)3*DIM*DIM*2;
  bf16* wprojb= (bf16*)ws;  ws += (size_t)DIM*DIM*2;
  bf16* qb    = (bf16*)ws;  ws += (size_t)BH_*N_*HD*2;
  bf16* kb    = (bf16*)ws;  ws += (size_t)BH_*N_*HD*2;
  bf16* vtb   = (bf16*)ws;  ws += (size_t)BH_*HD*N_*2;
  bf16* aob   = (bf16*)ws;  ws += (size_t)M_*DIM*2;

  convert_all<<<dim3(2048), dim3(256), 0, stream>>>(
      (const float4*)x, (const float4*)wqkv, (const float4*)wproj,
      (bf16x4*)xb, (bf16x4*)wqkvb, (bf16x4*)wprojb);

  gemm_bt<0><<<dim3(3*DIM/128, M_/128), dim3(256), 0, stream>>>(
      xb, wqkvb, qb, kb, vtb, nullptr, nullptr);

  attn_fwd<<<dim3(N_/128, BH_), dim3(256), 0, stream>>>(qb, kb, vtb, aob);

  gemm_bt<1><<<dim3(DIM/128, M_/128), dim3(256), 0, stream>>>(
      aob, wprojb, nullptr, nullptr, nullptr, bproj, out);
}